// Round 10
// baseline (185.110 us; speedup 1.0000x reference)
//
#include <hip/hip_runtime.h>
#include <math.h>

#define T_ 2048
#define H_ 16

typedef __attribute__((ext_vector_type(8))) short bfx8;   // 8 bf16 = 4 VGPRs
typedef __attribute__((ext_vector_type(4))) float f32x4;  // MFMA accumulator

__device__ __forceinline__ short f2bf(float f) {
  union { float f; unsigned u; } x; x.f = f;
  unsigned r = (x.u + 0x7FFFu + ((x.u >> 16) & 1u)) >> 16;  // RNE
  return (short)r;
}
__device__ __forceinline__ float bf2f(short s) {
  union { unsigned u; float f; } x;
  x.u = ((unsigned)(unsigned short)s) << 16;
  return x.f;
}

// ---------------- prep: weight cvt + RMSNorm + Cb basis + tk table + Mt/H zero
__global__ __launch_bounds__(256) void prep_kernel(
    const float* __restrict__ Wk, const float* __restrict__ Wv,
    const float* __restrict__ Wo, const float* __restrict__ angles,
    const float* __restrict__ states, const float* __restrict__ ln_w,
    short* __restrict__ Wkb, short* __restrict__ Wvb, short* __restrict__ Wob,
    short* __restrict__ xb, short* __restrict__ Cb, short* __restrict__ tkT,
    float* __restrict__ MtH) {
  const int blk = blockIdx.x;
  if (blk < 3072) {
    const int i = blk * 256 + threadIdx.x;
    const int which = i >> 18;
    const int idx = i & 262143;
    const float* s = (which == 0) ? Wk : (which == 1) ? Wv : Wo;
    short* d = (which == 0) ? Wkb : (which == 1) ? Wvb : Wob;
    const float4 v = ((const float4*)s)[idx];
    short4 r;
    r.x = f2bf(v.x); r.y = f2bf(v.y); r.z = f2bf(v.z); r.w = f2bf(v.w);
    ((short4*)d)[idx] = r;
  } else if (blk < 7168) {
    const int row = blk - 3072;
    const int tid = threadIdx.x;
    const float4 v = ((const float4*)(states + (size_t)row * 1024))[tid];
    float ss = v.x * v.x + v.y * v.y + v.z * v.z + v.w * v.w;
#pragma unroll
    for (int off = 32; off >= 1; off >>= 1) ss += __shfl_xor(ss, off);
    __shared__ float red[4];
    if ((tid & 63) == 0) red[tid >> 6] = ss;
    __syncthreads();
    const float tot = red[0] + red[1] + red[2] + red[3];
    const float scale = rsqrtf(tot * (1.0f / 1024.0f) + 1.1920928955078125e-07f);
    const float4 w = ((const float4*)ln_w)[tid];
    short4 o;
    o.x = f2bf(v.x * scale * w.x);
    o.y = f2bf(v.y * scale * w.y);
    o.z = f2bf(v.z * scale * w.z);
    o.w = f2bf(v.w * scale * w.w);
    ((short4*)(xb + (size_t)row * 1024))[tid] = o;
  } else if (blk < 7424) {
    const int gid = (blk - 7168) * 256 + threadIdx.x;  // 64K: (t,j)
    const int j = gid & 31;
    const int t = gid >> 5;
    float s, c;
    sincosf((float)t * angles[j], &s, &c);
    Cb[(size_t)t * 64 + j] = f2bf(0.125f * c);
    Cb[(size_t)t * 64 + 32 + j] = f2bf(0.125f * s);
  } else if (blk < 7456) {
    const int gid = (blk - 7424) * 256 + threadIdx.x;  // 8K: (j, l-chunk)
    const int tc = gid & 255;
    const int j = gid >> 8;
    const float th = angles[j];
    short lo[8], hi[8];
#pragma unroll
    for (int r = 0; r < 8; ++r) {
      float s, c;
      sincosf((float)(tc * 8 + r) * th, &s, &c);
      lo[r] = f2bf((c + s) * 0.125f);
      hi[r] = f2bf((c - s) * 0.125f);
    }
    short* base = tkT + (size_t)j * 2048 + tc * 8;
    *(short4*)(base) = *(short4*)&lo[0];
    *(short4*)(base + 4) = *(short4*)&lo[4];
    short* base2 = tkT + (size_t)(32 + j) * 2048 + tc * 8;
    *(short4*)(base2) = *(short4*)&hi[0];
    *(short4*)(base2 + 4) = *(short4*)&hi[4];
  } else {  // zero Mt (512 KB) + H (512 KB): 65536 float4s
    const int gid = (blk - 7456) * 256 + threadIdx.x;
    ((float4*)MtH)[gid] = make_float4(0.f, 0.f, 0.f, 0.f);
  }
}

// ------- fused K+V GEMM + masked softmax + kv + Mt accumulation -------------
// BARRIER-FREE K-loop: MFMA fragments loaded global->VGPR directly (no LDS,
// no __syncthreads => no vmcnt(0) drains). Lane (quad,lrow) loads 16B at
// row=i*16+lrow, k=k0+quad*8; each quad covers 64B contiguous per row.
// Full unroll lets the compiler hoist loads to AITER-style vmcnt(N) depth.
__global__ __launch_bounds__(256) void kvgemm_kernel(
    const short* __restrict__ xb, const short* __restrict__ Wkb,
    const short* __restrict__ Wvb, const float* __restrict__ bk,
    const float* __restrict__ bv, const int* __restrict__ mask,
    const short* __restrict__ tkT, float* __restrict__ Mt) {
  __shared__ short Vs[128][64];   // 16 KB
  __shared__ short kvS[64][132];  // 16.5 KB (padded: epilogue is VALU-written)

  const int row0 = blockIdx.x * 128;  // XCD = x%8
  const int h = blockIdx.y;
  const int t = threadIdx.x;
  const int lane = t & 63;
  const int wv = t >> 6;
  const bool isV = wv >= 2;
  const int wrow = (wv & 1) * 64;
  const int lrow = lane & 15;
  const int quad = lane >> 4;

  const short* Ab = xb + (size_t)(row0 + wrow + lrow) * 1024 + quad * 8;
  const short* Bb = (isV ? Wvb : Wkb) + (size_t)(h * 64 + lrow) * 1024 + quad * 8;

  f32x4 acc[4][4] = {};
  bfx8 aF[2][4], bF[2][4];
#pragma unroll
  for (int i = 0; i < 4; ++i) {
    aF[0][i] = *(const bfx8*)(Ab + (size_t)i * 16384);
    bF[0][i] = *(const bfx8*)(Bb + (size_t)i * 16384);
  }
#pragma unroll
  for (int it = 0; it < 32; ++it) {
    const int cur = it & 1, nxt = cur ^ 1;
    if (it < 31) {
      const int k1 = (it + 1) * 32;
#pragma unroll
      for (int i = 0; i < 4; ++i) {
        aF[nxt][i] = *(const bfx8*)(Ab + (size_t)i * 16384 + k1);
        bF[nxt][i] = *(const bfx8*)(Bb + (size_t)i * 16384 + k1);
      }
    }
#pragma unroll
    for (int i = 0; i < 4; ++i)
#pragma unroll
      for (int j = 0; j < 4; ++j)
        acc[i][j] = __builtin_amdgcn_mfma_f32_16x16x32_bf16(aF[cur][i], bF[cur][j], acc[i][j], 0, 0, 0);
  }
  const int rq = quad * 4;
  if (isV) {  // park V+bias in Vs
#pragma unroll
    for (int j = 0; j < 4; ++j) {
      const float bb = bv[h * 64 + j * 16 + lrow];
#pragma unroll
      for (int i = 0; i < 4; ++i)
#pragma unroll
        for (int rr = 0; rr < 4; ++rr)
          Vs[wrow + rq + i * 16 + rr][j * 16 + lrow] = f2bf(acc[i][j][rr] + bb);
    }
  }
  __syncthreads();
  if (!isV) {  // masked softmax over head dim, kv = softmax * V -> kvS[d][l]
    float bkc[4];
#pragma unroll
    for (int j = 0; j < 4; ++j) bkc[j] = bk[h * 64 + j * 16 + lrow];
    const int rowg0 = row0 + wrow + rq;
#pragma unroll
    for (int i = 0; i < 4; ++i) {
#pragma unroll
      for (int rr = 0; rr < 4; ++rr) {
        const float m = (float)mask[rowg0 + i * 16 + rr];
        float kf[4];
#pragma unroll
        for (int j = 0; j < 4; ++j) kf[j] = (acc[i][j][rr] + bkc[j]) * m;
        float mx = fmaxf(fmaxf(kf[0], kf[1]), fmaxf(kf[2], kf[3]));
#pragma unroll
        for (int off = 8; off >= 1; off >>= 1) mx = fmaxf(mx, __shfl_xor(mx, off));
        float s = 0.0f;
#pragma unroll
        for (int j = 0; j < 4; ++j) { kf[j] = expf(kf[j] - mx); s += kf[j]; }
#pragma unroll
        for (int off = 8; off >= 1; off >>= 1) s += __shfl_xor(s, off);
        const float inv = 1.0f / s;
#pragma unroll
        for (int j = 0; j < 4; ++j)
          acc[i][j][rr] = kf[j] * inv *
                          bf2f(Vs[wrow + rq + i * 16 + rr][j * 16 + lrow]);
      }
    }
#pragma unroll
    for (int j = 0; j < 4; ++j) {
      const int d = j * 16 + lrow;
#pragma unroll
      for (int i = 0; i < 4; ++i) {
        short4 o;
        o.x = f2bf(acc[i][j][0]); o.y = f2bf(acc[i][j][1]);
        o.z = f2bf(acc[i][j][2]); o.w = f2bf(acc[i][j][3]);
        *(short4*)&kvS[d][wrow + rq + i * 16] = o;
      }
    }
  }
  __syncthreads();
  // Mt contraction: wave wv covers e in [wv*16, wv*16+16), K = 128 local l.
  const int bb = row0 >> 11;
  const int tb = row0 & 2047;
  const short* tkb = tkT + (size_t)(wv * 16 + lrow) * 2048 + tb;
  const int kg = quad * 8;
  f32x4 macc[4] = {};
#pragma unroll
  for (int kc = 0; kc < 4; ++kc) {
    const bfx8 af = *(const bfx8*)(tkb + kc * 32 + kg);
#pragma unroll
    for (int j = 0; j < 4; ++j) {
      const bfx8 bf_ = *(const bfx8*)&kvS[j * 16 + lrow][kc * 32 + kg];
      macc[j] = __builtin_amdgcn_mfma_f32_16x16x32_bf16(af, bf_, macc[j], 0, 0, 0);
    }
  }
  float* Mb = Mt + (size_t)(bb * 16 + h) * 4096;
#pragma unroll
  for (int j = 0; j < 4; ++j) {
    const int d = j * 16 + lrow;
#pragma unroll
    for (int rr = 0; rr < 4; ++rr) {
      const int e = wv * 16 + rq + rr;
      atomicAdd(&Mb[(size_t)e * 64 + d], macc[j][rr]);
    }
  }
}

// ---------------- fold: Mf[b][j][h*64+d]    = p*Mt[b,h][j][d] + q*Mt[b,h][32+j][d]
//                        Mf[b][32+j][h*64+d] = q*Mt[b,h][j][d] - p*Mt[b,h][32+j][d]
__global__ __launch_bounds__(256) void fold_kernel(
    const float* __restrict__ Mt, const float* __restrict__ angles,
    const float* __restrict__ delta, short* __restrict__ Mf) {
  const int bh = blockIdx.x;
  const int b = bh >> 4, h = bh & 15;
  const int t = threadIdx.x;
  const int j = t >> 3;
  const int d8 = (t & 7) * 8;
  float sphi, cphi;
  sincosf(delta[h] * angles[j], &sphi, &cphi);
  const float p = cphi + sphi, q = cphi - sphi;
  const float* m0 = Mt + (size_t)bh * 4096 + (size_t)j * 64 + d8;
  const float* m1 = Mt + (size_t)bh * 4096 + (size_t)(32 + j) * 64 + d8;
  short* oc = Mf + (size_t)b * 65536 + (size_t)j * 1024 + h * 64 + d8;
  short* os = Mf + (size_t)b * 65536 + (size_t)(32 + j) * 1024 + h * 64 + d8;
#pragma unroll
  for (int c = 0; c < 8; ++c) {
    const float a = m0[c], bb = m1[c];
    oc[c] = f2bf(p * a + q * bb);
    os[c] = f2bf(q * a - p * bb);
  }
}

// ---------------- H[b][o][kap] += sum_k Wob[o][k] * Mf[b][kap][k], split-K=8
__global__ __launch_bounds__(256) void hgemm_kernel(
    const short* __restrict__ Wob, const short* __restrict__ Mf,
    float* __restrict__ H) {
  const int kc = blockIdx.x;
  const int o0 = blockIdx.y * 64;
  const int b = blockIdx.z;
  const int t = threadIdx.x;
  const int lane = t & 63;
  const int w = t >> 6;
  const int lrow = lane & 15;
  const int kg = (lane >> 4) * 8;
  const int orow = o0 + w * 16 + lrow;
  f32x4 acc[4] = {};
#pragma unroll
  for (int it = 0; it < 4; ++it) {
    const int kb = kc * 128 + it * 32 + kg;
    const bfx8 af = *(const bfx8*)(Wob + (size_t)orow * 1024 + kb);
#pragma unroll
    for (int j = 0; j < 4; ++j) {
      const bfx8 bf_ = *(const bfx8*)(Mf + (size_t)b * 65536 +
                                      (size_t)(j * 16 + lrow) * 1024 + kb);
      acc[j] = __builtin_amdgcn_mfma_f32_16x16x32_bf16(af, bf_, acc[j], 0, 0, 0);
    }
  }
  float* Hb = H + (size_t)b * 65536;
#pragma unroll
  for (int j = 0; j < 4; ++j) {
    const int kap = j * 16 + lrow;
#pragma unroll
    for (int rr = 0; rr < 4; ++rr) {
      const int o = o0 + w * 16 + (lane >> 4) * 4 + rr;
      atomicAdd(&Hb[(size_t)o * 64 + kap], acc[j][rr]);
    }
  }
}

// ---------------- out[b][t][o] = sum_kap Cb[t][kap]*H[b][o][kap] + bo[o] ------
__global__ __launch_bounds__(256) void ofinal_kernel(
    const short* __restrict__ Cb, const float* __restrict__ H,
    const float* __restrict__ bo, float* __restrict__ out) {
  const int col0 = blockIdx.x * 128;
  const int row0 = blockIdx.y * 128;
  const int b = blockIdx.z;
  float* C = out + (size_t)b * 2097152;
  const float* Hb = H + (size_t)b * 65536;
  const int t = threadIdx.x;
  const int lane = t & 63;
  const int wv = t >> 6;
  const int wm = (wv & 1) * 64, wn = (wv >> 1) * 64;
  const int lrow = lane & 15;
  const int kg = (lane >> 4) * 8;
  f32x4 acc[4][4] = {};
#pragma unroll
  for (int k0 = 0; k0 < 64; k0 += 32) {
    bfx8 af[4], bf_[4];
#pragma unroll
    for (int i = 0; i < 4; ++i)
      af[i] = *(const bfx8*)(Cb + (size_t)(row0 + wm + i * 16 + lrow) * 64 + k0 + kg);
#pragma unroll
    for (int j = 0; j < 4; ++j) {
      const float* hp = Hb + (size_t)(col0 + wn + j * 16 + lrow) * 64 + k0 + kg;
      const float4 h0 = *(const float4*)hp;
      const float4 h1 = *(const float4*)(hp + 4);
      bfx8 bb;
      bb[0] = f2bf(h0.x); bb[1] = f2bf(h0.y); bb[2] = f2bf(h0.z); bb[3] = f2bf(h0.w);
      bb[4] = f2bf(h1.x); bb[5] = f2bf(h1.y); bb[6] = f2bf(h1.z); bb[7] = f2bf(h1.w);
      bf_[j] = bb;
    }
#pragma unroll
    for (int i = 0; i < 4; ++i)
#pragma unroll
      for (int j = 0; j < 4; ++j)
        acc[i][j] = __builtin_amdgcn_mfma_f32_16x16x32_bf16(af[i], bf_[j], acc[i][j], 0, 0, 0);
  }
  const int rq = (lane >> 4) * 4;
#pragma unroll
  for (int j = 0; j < 4; ++j) {
    const int c = col0 + wn + j * 16 + lrow;
    const float bb = bo[c];
#pragma unroll
    for (int i = 0; i < 4; ++i) {
      const int r = row0 + wm + i * 16 + rq;
#pragma unroll
      for (int rr = 0; rr < 4; ++rr)
        C[(size_t)(r + rr) * 1024 + c] = acc[i][j][rr] + bb;
    }
  }
}

extern "C" void kernel_launch(void* const* d_in, const int* in_sizes, int n_in,
                              void* d_out, int out_size, void* d_ws, size_t ws_size,
                              hipStream_t stream) {
  (void)in_sizes; (void)n_in; (void)out_size; (void)ws_size;
  const float* states = (const float*)d_in[0];
  const int* mask = (const int*)d_in[1];
  const float* ln_w = (const float*)d_in[2];
  const float* angles = (const float*)d_in[3];
  const float* delta = (const float*)d_in[4];
  // d_in[5]=Wq, d_in[6]=q_bias provably unused (softmax row-sums are 1).
  const float* Wk = (const float*)d_in[7];
  const float* bk = (const float*)d_in[8];
  const float* Wv = (const float*)d_in[9];
  const float* bv = (const float*)d_in[10];
  const float* Wo = (const float*)d_in[11];
  const float* bo = (const float*)d_in[12];
  float* out = (float*)d_out;

  char* W = (char*)d_ws;
  short* xb  = (short*)(W);                        // 8 MB   [4096][1024]
  short* Wkb = (short*)(W + (8u << 20));           // 2 MB
  short* Wvb = (short*)(W + (10u << 20));          // 2 MB
  short* Wob = (short*)(W + (12u << 20));          // 2 MB
  short* Cb  = (short*)(W + (14u << 20));          // 256 KB [2048][64]
  short* tkT = (short*)(W + (14u << 20) + (256u << 10));  // 256 KB [64][2048]
  short* Mf  = (short*)(W + (14u << 20) + (512u << 10));  // 256 KB [2][64][1024]
  float* Mt  = (float*)(W + (15u << 20));          // 512 KB [32][64][64]
  float* H   = (float*)(W + (15u << 20) + (512u << 10));  // 512 KB [2][1024][64]

  prep_kernel<<<7712, 256, 0, stream>>>(Wk, Wv, Wo, angles, states, ln_w,
                                        Wkb, Wvb, Wob, xb, Cb, tkT, Mt);
  kvgemm_kernel<<<dim3(32, 16), 256, 0, stream>>>(xb, Wkb, Wvb, bk, bv, mask,
                                                  tkT, Mt);
  fold_kernel<<<32, 256, 0, stream>>>(Mt, angles, delta, Mf);
  hgemm_kernel<<<dim3(8, 16, 2), 256, 0, stream>>>(Wob, Mf, H);
  ofinal_kernel<<<dim3(8, 16, 2), 256, 0, stream>>>(Cb, H, bo, out);
}

// Round 11
// 149.543 us; speedup vs baseline: 1.2378x; 1.2378x over previous
//
#include <hip/hip_runtime.h>
#include <math.h>

#define T_ 2048
#define H_ 16

typedef __attribute__((ext_vector_type(8))) short bfx8;   // 8 bf16 = 4 VGPRs
typedef __attribute__((ext_vector_type(4))) float f32x4;  // MFMA accumulator

__device__ __forceinline__ short f2bf(float f) {
  union { float f; unsigned u; } x; x.f = f;
  unsigned r = (x.u + 0x7FFFu + ((x.u >> 16) & 1u)) >> 16;  // RNE
  return (short)r;
}
__device__ __forceinline__ float bf2f(short s) {
  union { unsigned u; float f; } x;
  x.u = ((unsigned)(unsigned short)s) << 16;
  return x.f;
}

#define GLD_LDS(g, l) \
  __builtin_amdgcn_global_load_lds( \
      (const __attribute__((address_space(1))) void*)(g), \
      (__attribute__((address_space(3))) void*)(l), 16, 0, 0)

// ---------------- prep: weight cvt + RMSNorm + Cb basis + tk table + Mt/H zero
__global__ __launch_bounds__(256) void prep_kernel(
    const float* __restrict__ Wk, const float* __restrict__ Wv,
    const float* __restrict__ Wo, const float* __restrict__ angles,
    const float* __restrict__ states, const float* __restrict__ ln_w,
    short* __restrict__ Wkb, short* __restrict__ Wvb, short* __restrict__ Wob,
    short* __restrict__ xb, short* __restrict__ Cb, short* __restrict__ tkT,
    float* __restrict__ MtH) {
  const int blk = blockIdx.x;
  if (blk < 3072) {
    const int i = blk * 256 + threadIdx.x;
    const int which = i >> 18;
    const int idx = i & 262143;
    const float* s = (which == 0) ? Wk : (which == 1) ? Wv : Wo;
    short* d = (which == 0) ? Wkb : (which == 1) ? Wvb : Wob;
    const float4 v = ((const float4*)s)[idx];
    short4 r;
    r.x = f2bf(v.x); r.y = f2bf(v.y); r.z = f2bf(v.z); r.w = f2bf(v.w);
    ((short4*)d)[idx] = r;
  } else if (blk < 7168) {
    const int row = blk - 3072;
    const int tid = threadIdx.x;
    const float4 v = ((const float4*)(states + (size_t)row * 1024))[tid];
    float ss = v.x * v.x + v.y * v.y + v.z * v.z + v.w * v.w;
#pragma unroll
    for (int off = 32; off >= 1; off >>= 1) ss += __shfl_xor(ss, off);
    __shared__ float red[4];
    if ((tid & 63) == 0) red[tid >> 6] = ss;
    __syncthreads();
    const float tot = red[0] + red[1] + red[2] + red[3];
    const float scale = rsqrtf(tot * (1.0f / 1024.0f) + 1.1920928955078125e-07f);
    const float4 w = ((const float4*)ln_w)[tid];
    short4 o;
    o.x = f2bf(v.x * scale * w.x);
    o.y = f2bf(v.y * scale * w.y);
    o.z = f2bf(v.z * scale * w.z);
    o.w = f2bf(v.w * scale * w.w);
    ((short4*)(xb + (size_t)row * 1024))[tid] = o;
  } else if (blk < 7424) {
    const int gid = (blk - 7168) * 256 + threadIdx.x;  // 64K: (t,j)
    const int j = gid & 31;
    const int t = gid >> 5;
    float s, c;
    sincosf((float)t * angles[j], &s, &c);
    Cb[(size_t)t * 64 + j] = f2bf(0.125f * c);
    Cb[(size_t)t * 64 + 32 + j] = f2bf(0.125f * s);
  } else if (blk < 7456) {
    const int gid = (blk - 7424) * 256 + threadIdx.x;  // 8K: (j, l-chunk)
    const int tc = gid & 255;
    const int j = gid >> 8;
    const float th = angles[j];
    short lo[8], hi[8];
#pragma unroll
    for (int r = 0; r < 8; ++r) {
      float s, c;
      sincosf((float)(tc * 8 + r) * th, &s, &c);
      lo[r] = f2bf((c + s) * 0.125f);
      hi[r] = f2bf((c - s) * 0.125f);
    }
    short* base = tkT + (size_t)j * 2048 + tc * 8;
    *(short4*)(base) = *(short4*)&lo[0];
    *(short4*)(base + 4) = *(short4*)&lo[4];
    short* base2 = tkT + (size_t)(32 + j) * 2048 + tc * 8;
    *(short4*)(base2) = *(short4*)&hi[0];
    *(short4*)(base2 + 4) = *(short4*)&hi[4];
  } else {  // zero Mt (512 KB) + H (512 KB): 65536 float4s
    const int gid = (blk - 7456) * 256 + threadIdx.x;
    ((float4*)MtH)[gid] = make_float4(0.f, 0.f, 0.f, 0.f);
  }
}

// ------- fused K+V GEMM + masked softmax + kv + Mt accumulation -------------
// r7 structure (128 rows x 1 head, grid 512, BK=64, XOR-8 swizzle, DMA+barrier
// K-loop) but with 512-THREAD BLOCKS (8 waves): same total MFMA and DMA-instr
// count, same 48 KB LDS, but 16 waves/CU = 4 waves/SIMD -> wave-level overlap
// (m114) absorbs the per-barrier drains that 2 waves/SIMD could not.
// Wave roles: isV = wave>=4; sub=wave&3: wrow=(sub&1)*64, ihalf=sub>>1 picks
// 2 of 4 row-fragments. Each wave: acc[2][4] (32 rows x 64 cols).
__global__ __launch_bounds__(512) void kvgemm_kernel(
    const short* __restrict__ xb, const short* __restrict__ Wkb,
    const short* __restrict__ Wvb, const float* __restrict__ bk,
    const float* __restrict__ bv, const int* __restrict__ mask,
    const short* __restrict__ tkT, float* __restrict__ Mt) {
  __shared__ short smem[16384];  // As[128][64] 16KB | Bk[64][64] 8KB | Bv 8KB
  __shared__ short Vs[128][64];  // 16 KB   (total 48 KB)
  short(*As)[64] = (short(*)[64])smem;
  short(*Bk)[64] = (short(*)[64])(smem + 8192);
  short(*Bv)[64] = (short(*)[64])(smem + 12288);
  short(*kvS)[132] = (short(*)[132])smem;  // overlay post-loop (16.5KB < 32KB)

  const int row0 = blockIdx.x * 128;  // XCD = x%8
  const int h = blockIdx.y;
  const int t = threadIdx.x;
  const int lane = t & 63;
  const int wave = t >> 6;
  const bool isV = wave >= 4;
  const int sub = wave & 3;
  const int wrow = (sub & 1) * 64;
  const int ihalf = sub >> 1;          // which 2 of 4 row-fragments
  const int rbase = wrow + ihalf * 32; // wave's 32-row base
  const int lrow = lane & 15;
  const int quad = lane >> 4;

  // staging: 512 threads cover 64 rows/issue; thread t owns phys slot t&7 of
  // row t>>3; fetches k-slot (t&7)^(row&7). Per-wave LDS dest = base+lane*16.
  const int srow8 = t >> 3;            // 0..63
  const int kslotS = (t & 7) ^ (srow8 & 7);
  const short* gaS = xb + (size_t)(row0 + srow8) * 1024 + kslotS * 8;
  const short* gkS = Wkb + (size_t)(h * 64 + srow8) * 1024 + kslotS * 8;
  const short* gvS = Wvb + (size_t)(h * 64 + srow8) * 1024 + kslotS * 8;
  const int sc = (t & 7) * 8;

  f32x4 acc[2][4] = {};
  for (int k0 = 0; k0 < 1024; k0 += 64) {
    GLD_LDS(gaS + k0, &As[srow8][sc]);
    GLD_LDS(gaS + 64 * 1024 + k0, &As[srow8 + 64][sc]);
    GLD_LDS(gkS + k0, &Bk[srow8][sc]);
    GLD_LDS(gvS + k0, &Bv[srow8][sc]);
    __syncthreads();
#pragma unroll
    for (int kk = 0; kk < 2; ++kk) {
      const int pcol = ((kk * 4 + quad) ^ (lrow & 7)) * 8;
      bfx8 af[2], bf_[4];
#pragma unroll
      for (int i = 0; i < 2; ++i)
        af[i] = *(const bfx8*)&As[rbase + i * 16 + lrow][pcol];
      const short(*Bs)[64] = isV ? Bv : Bk;
#pragma unroll
      for (int j = 0; j < 4; ++j)
        bf_[j] = *(const bfx8*)&Bs[j * 16 + lrow][pcol];
#pragma unroll
      for (int i = 0; i < 2; ++i)
#pragma unroll
        for (int j = 0; j < 4; ++j)
          acc[i][j] = __builtin_amdgcn_mfma_f32_16x16x32_bf16(af[i], bf_[j], acc[i][j], 0, 0, 0);
    }
    __syncthreads();
  }
  const int rq = quad * 4;
  if (isV) {  // park V+bias in Vs (each V wave: its 32 rows)
#pragma unroll
    for (int j = 0; j < 4; ++j) {
      const float bb = bv[h * 64 + j * 16 + lrow];
#pragma unroll
      for (int i = 0; i < 2; ++i)
#pragma unroll
        for (int rr = 0; rr < 4; ++rr)
          Vs[rbase + rq + i * 16 + rr][j * 16 + lrow] = f2bf(acc[i][j][rr] + bb);
    }
  }
  __syncthreads();
  if (!isV) {  // masked softmax over head dim, kv = softmax * V -> kvS[d][l]
    float bkc[4];
#pragma unroll
    for (int j = 0; j < 4; ++j) bkc[j] = bk[h * 64 + j * 16 + lrow];
#pragma unroll
    for (int i = 0; i < 2; ++i) {
#pragma unroll
      for (int rr = 0; rr < 4; ++rr) {
        const int row = rbase + rq + i * 16 + rr;
        const float m = (float)mask[row0 + row];
        float kf[4];
#pragma unroll
        for (int j = 0; j < 4; ++j) kf[j] = (acc[i][j][rr] + bkc[j]) * m;
        float mx = fmaxf(fmaxf(kf[0], kf[1]), fmaxf(kf[2], kf[3]));
#pragma unroll
        for (int off = 8; off >= 1; off >>= 1) mx = fmaxf(mx, __shfl_xor(mx, off));
        float s = 0.0f;
#pragma unroll
        for (int j = 0; j < 4; ++j) { kf[j] = expf(kf[j] - mx); s += kf[j]; }
#pragma unroll
        for (int off = 8; off >= 1; off >>= 1) s += __shfl_xor(s, off);
        const float inv = 1.0f / s;
#pragma unroll
        for (int j = 0; j < 4; ++j)
          acc[i][j][rr] = kf[j] * inv * bf2f(Vs[row][j * 16 + lrow]);
      }
    }
#pragma unroll
    for (int j = 0; j < 4; ++j) {
      const int d = j * 16 + lrow;
#pragma unroll
      for (int i = 0; i < 2; ++i) {
        short4 o;
        o.x = f2bf(acc[i][j][0]); o.y = f2bf(acc[i][j][1]);
        o.z = f2bf(acc[i][j][2]); o.w = f2bf(acc[i][j][3]);
        *(short4*)&kvS[d][rbase + rq + i * 16] = o;
      }
    }
  }
  __syncthreads();
  // Mt contraction: e-slice = (wave&3)*16; waves w and w+4 share the slice,
  // splitting the 4 kc chunks 2+2. fp32 atomics absorb the overlap.
  const int bb = row0 >> 11;
  const int tb = row0 & 2047;
  const int e0 = (wave & 3) * 16;
  const int kc0 = (wave >> 2) * 2;
  const short* tkb = tkT + (size_t)(e0 + lrow) * 2048 + tb;
  const int kg = quad * 8;
  f32x4 macc[4] = {};
#pragma unroll
  for (int kc = 0; kc < 2; ++kc) {
    const bfx8 af = *(const bfx8*)(tkb + (kc0 + kc) * 32 + kg);
#pragma unroll
    for (int j = 0; j < 4; ++j) {
      const bfx8 bf_ = *(const bfx8*)&kvS[j * 16 + lrow][(kc0 + kc) * 32 + kg];
      macc[j] = __builtin_amdgcn_mfma_f32_16x16x32_bf16(af, bf_, macc[j], 0, 0, 0);
    }
  }
  float* Mb = Mt + (size_t)(bb * 16 + h) * 4096;
#pragma unroll
  for (int j = 0; j < 4; ++j) {
    const int d = j * 16 + lrow;
#pragma unroll
    for (int rr = 0; rr < 4; ++rr) {
      const int e = e0 + rq + rr;
      atomicAdd(&Mb[(size_t)e * 64 + d], macc[j][rr]);
    }
  }
}

// ---------------- fold: Mf[b][j][h*64+d]    = p*Mt[b,h][j][d] + q*Mt[b,h][32+j][d]
//                        Mf[b][32+j][h*64+d] = q*Mt[b,h][j][d] - p*Mt[b,h][32+j][d]
__global__ __launch_bounds__(256) void fold_kernel(
    const float* __restrict__ Mt, const float* __restrict__ angles,
    const float* __restrict__ delta, short* __restrict__ Mf) {
  const int bh = blockIdx.x;
  const int b = bh >> 4, h = bh & 15;
  const int t = threadIdx.x;
  const int j = t >> 3;
  const int d8 = (t & 7) * 8;
  float sphi, cphi;
  sincosf(delta[h] * angles[j], &sphi, &cphi);
  const float p = cphi + sphi, q = cphi - sphi;
  const float* m0 = Mt + (size_t)bh * 4096 + (size_t)j * 64 + d8;
  const float* m1 = Mt + (size_t)bh * 4096 + (size_t)(32 + j) * 64 + d8;
  short* oc = Mf + (size_t)b * 65536 + (size_t)j * 1024 + h * 64 + d8;
  short* os = Mf + (size_t)b * 65536 + (size_t)(32 + j) * 1024 + h * 64 + d8;
#pragma unroll
  for (int c = 0; c < 8; ++c) {
    const float a = m0[c], bb = m1[c];
    oc[c] = f2bf(p * a + q * bb);
    os[c] = f2bf(q * a - p * bb);
  }
}

// ---------------- H[b][o][kap] += sum_k Wob[o][k] * Mf[b][kap][k], split-K=8
__global__ __launch_bounds__(256) void hgemm_kernel(
    const short* __restrict__ Wob, const short* __restrict__ Mf,
    float* __restrict__ H) {
  const int kc = blockIdx.x;
  const int o0 = blockIdx.y * 64;
  const int b = blockIdx.z;
  const int t = threadIdx.x;
  const int lane = t & 63;
  const int w = t >> 6;
  const int lrow = lane & 15;
  const int kg = (lane >> 4) * 8;
  const int orow = o0 + w * 16 + lrow;
  f32x4 acc[4] = {};
#pragma unroll
  for (int it = 0; it < 4; ++it) {
    const int kb = kc * 128 + it * 32 + kg;
    const bfx8 af = *(const bfx8*)(Wob + (size_t)orow * 1024 + kb);
#pragma unroll
    for (int j = 0; j < 4; ++j) {
      const bfx8 bf_ = *(const bfx8*)(Mf + (size_t)b * 65536 +
                                      (size_t)(j * 16 + lrow) * 1024 + kb);
      acc[j] = __builtin_amdgcn_mfma_f32_16x16x32_bf16(af, bf_, acc[j], 0, 0, 0);
    }
  }
  float* Hb = H + (size_t)b * 65536;
#pragma unroll
  for (int j = 0; j < 4; ++j) {
    const int kap = j * 16 + lrow;
#pragma unroll
    for (int rr = 0; rr < 4; ++rr) {
      const int o = o0 + w * 16 + (lane >> 4) * 4 + rr;
      atomicAdd(&Hb[(size_t)o * 64 + kap], acc[j][rr]);
    }
  }
}

// ---------------- out[b][t][o] = sum_kap Cb[t][kap]*H[b][o][kap] + bo[o] ------
__global__ __launch_bounds__(256) void ofinal_kernel(
    const short* __restrict__ Cb, const float* __restrict__ H,
    const float* __restrict__ bo, float* __restrict__ out) {
  const int col0 = blockIdx.x * 128;
  const int row0 = blockIdx.y * 128;
  const int b = blockIdx.z;
  float* C = out + (size_t)b * 2097152;
  const float* Hb = H + (size_t)b * 65536;
  const int t = threadIdx.x;
  const int lane = t & 63;
  const int wv = t >> 6;
  const int wm = (wv & 1) * 64, wn = (wv >> 1) * 64;
  const int lrow = lane & 15;
  const int kg = (lane >> 4) * 8;
  f32x4 acc[4][4] = {};
#pragma unroll
  for (int k0 = 0; k0 < 64; k0 += 32) {
    bfx8 af[4], bf_[4];
#pragma unroll
    for (int i = 0; i < 4; ++i)
      af[i] = *(const bfx8*)(Cb + (size_t)(row0 + wm + i * 16 + lrow) * 64 + k0 + kg);
#pragma unroll
    for (int j = 0; j < 4; ++j) {
      const float* hp = Hb + (size_t)(col0 + wn + j * 16 + lrow) * 64 + k0 + kg;
      const float4 h0 = *(const float4*)hp;
      const float4 h1 = *(const float4*)(hp + 4);
      bfx8 bb;
      bb[0] = f2bf(h0.x); bb[1] = f2bf(h0.y); bb[2] = f2bf(h0.z); bb[3] = f2bf(h0.w);
      bb[4] = f2bf(h1.x); bb[5] = f2bf(h1.y); bb[6] = f2bf(h1.z); bb[7] = f2bf(h1.w);
      bf_[j] = bb;
    }
#pragma unroll
    for (int i = 0; i < 4; ++i)
#pragma unroll
      for (int j = 0; j < 4; ++j)
        acc[i][j] = __builtin_amdgcn_mfma_f32_16x16x32_bf16(af[i], bf_[j], acc[i][j], 0, 0, 0);
  }
  const int rq = (lane >> 4) * 4;
#pragma unroll
  for (int j = 0; j < 4; ++j) {
    const int c = col0 + wn + j * 16 + lrow;
    const float bb = bo[c];
#pragma unroll
    for (int i = 0; i < 4; ++i) {
      const int r = row0 + wm + i * 16 + rq;
#pragma unroll
      for (int rr = 0; rr < 4; ++rr)
        C[(size_t)(r + rr) * 1024 + c] = acc[i][j][rr] + bb;
    }
  }
}

extern "C" void kernel_launch(void* const* d_in, const int* in_sizes, int n_in,
                              void* d_out, int out_size, void* d_ws, size_t ws_size,
                              hipStream_t stream) {
  (void)in_sizes; (void)n_in; (void)out_size; (void)ws_size;
  const float* states = (const float*)d_in[0];
  const int* mask = (const int*)d_in[1];
  const float* ln_w = (const float*)d_in[2];
  const float* angles = (const float*)d_in[3];
  const float* delta = (const float*)d_in[4];
  // d_in[5]=Wq, d_in[6]=q_bias provably unused (softmax row-sums are 1).
  const float* Wk = (const float*)d_in[7];
  const float* bk = (const float*)d_in[8];
  const float* Wv = (const float*)d_in[9];
  const float* bv = (const float*)d_in[10];
  const float* Wo = (const float*)d_in[11];
  const float* bo = (const float*)d_in[12];
  float* out = (float*)d_out;

  char* W = (char*)d_ws;
  short* xb  = (short*)(W);                        // 8 MB   [4096][1024]
  short* Wkb = (short*)(W + (8u << 20));           // 2 MB
  short* Wvb = (short*)(W + (10u << 20));          // 2 MB
  short* Wob = (short*)(W + (12u << 20));          // 2 MB
  short* Cb  = (short*)(W + (14u << 20));          // 256 KB [2048][64]
  short* tkT = (short*)(W + (14u << 20) + (256u << 10));  // 256 KB [64][2048]
  short* Mf  = (short*)(W + (14u << 20) + (512u << 10));  // 256 KB [2][64][1024]
  float* Mt  = (float*)(W + (15u << 20));          // 512 KB [32][64][64]
  float* H   = (float*)(W + (15u << 20) + (512u << 10));  // 512 KB [2][1024][64]

  prep_kernel<<<7712, 256, 0, stream>>>(Wk, Wv, Wo, angles, states, ln_w,
                                        Wkb, Wvb, Wob, xb, Cb, tkT, Mt);
  kvgemm_kernel<<<dim3(32, 16), 512, 0, stream>>>(xb, Wkb, Wvb, bk, bv, mask,
                                                  tkT, Mt);
  fold_kernel<<<32, 256, 0, stream>>>(Mt, angles, delta, Mf);
  hgemm_kernel<<<dim3(8, 16, 2), 256, 0, stream>>>(Wob, Mf, H);
  ofinal_kernel<<<dim3(8, 16, 2), 256, 0, stream>>>(Cb, H, bo, out);
}